// Round 7
// baseline (318.286 us; speedup 1.0000x reference)
//
#include <hip/hip_runtime.h>
#include <hip/hip_bf16.h>

// NoisyActLin: y = fakequant(x) @ fakequant(W).T + bias
// x: [4,2048,2048] f32 -> M=8192, K=2048 ; W: [8192,2048] f32 -> N=8192
// out: [8192, 8192] f32
//
// GEMM: 256x256 tile, BK=64, 8 waves (2Mx4N), per-wave 128x64.
// 8 phases / 2 K-tiles, ONE barrier per phase, fragment ds_reads pipelined
// one phase ahead with COUNTED lgkm waits, counted vmcnt(2) at P4/P8 only,
// T2 swizzle byte^=(row&7)<<4, setprio around MFMA.

using f16x8 = __attribute__((ext_vector_type(8))) _Float16;
using f32x4 = __attribute__((ext_vector_type(4))) float;

#define AS1 __attribute__((address_space(1)))
#define AS3 __attribute__((address_space(3)))

static __device__ __forceinline__ void gload_lds16(const void* g, void* l) {
    __builtin_amdgcn_global_load_lds((const AS1 void*)g, (AS3 void*)l, 16, 0, 0);
}

// ---------------- weight fake-quant: one block per row ----------------
__global__ __launch_bounds__(256) void wquant_kernel(
    const float* __restrict__ W, const float* __restrict__ lws,
    _Float16* __restrict__ Wq) {
    constexpr int K = 2048;
    const int row = blockIdx.x;
    const int t = threadIdx.x;
    const float* w = W + (size_t)row * K;

    float4 v0 = ((const float4*)w)[t * 2];
    float4 v1 = ((const float4*)w)[t * 2 + 1];
    float vals[8] = {v0.x, v0.y, v0.z, v0.w, v1.x, v1.y, v1.z, v1.w};

    float mn = vals[0], mx = vals[0];
#pragma unroll
    for (int i = 1; i < 8; ++i) {
        mn = fminf(mn, vals[i]);
        mx = fmaxf(mx, vals[i]);
    }
#pragma unroll
    for (int off = 32; off >= 1; off >>= 1) {
        mn = fminf(mn, __shfl_xor(mn, off));
        mx = fmaxf(mx, __shfl_xor(mx, off));
    }
    __shared__ float smn[4], smx[4];
    if ((t & 63) == 0) { smn[t >> 6] = mn; smx[t >> 6] = mx; }
    __syncthreads();
    mn = fminf(fminf(smn[0], smn[1]), fminf(smn[2], smn[3]));
    mx = fmaxf(fmaxf(smx[0], smx[1]), fmaxf(smx[2], smx[3]));

    const float l = lws[row];
    const float ws = exp2f(l);     // power of two -> exact
    const float rs = exp2f(-l);    // exact reciprocal
    const float qwmin = rintf(mn * rs * 2.0f) * 0.5f * ws;
    const float qwmax = rintf(mx * rs * 2.0f) * 0.5f * ws;

    f16x8 out;
#pragma unroll
    for (int i = 0; i < 8; ++i) {
        float c = fminf(fmaxf(vals[i], qwmin), qwmax);
        float qw = rintf((c - qwmin) * rs);
        out[i] = (_Float16)(qw * ws + qwmin);
    }
    *(f16x8*)&Wq[(size_t)row * K + (size_t)t * 8] = out;
}

// ---------------- activation fake-quant: elementwise ----------------
__global__ __launch_bounds__(256) void xquant_kernel(
    const float* __restrict__ X,
    const float* __restrict__ las, const float* __restrict__ laq,
    const float* __restrict__ ab, _Float16* __restrict__ Xq) {
    const float ls = las[0], lq = laq[0];
    const float s = exp2f(ls);
    const float rs = exp2f(-ls);
    const float q = exp2f(lq);
    const float zp = rintf(ab[0] * rs * 2.0f) * 0.5f * s;
    const float lo = zp;
    const float hi = (zp + q) - s;

    const size_t base = ((size_t)blockIdx.x * 256 + threadIdx.x) * 8;
    float4 v0 = *(const float4*)&X[base];
    float4 v1 = *(const float4*)&X[base + 4];
    float vals[8] = {v0.x, v0.y, v0.z, v0.w, v1.x, v1.y, v1.z, v1.w};

    f16x8 out;
#pragma unroll
    for (int i = 0; i < 8; ++i) {
        float c = fminf(fmaxf(vals[i], lo), hi);
        float qx = rintf((c - zp) * rs);
        out[i] = (_Float16)(qx * s + zp);
    }
    *(f16x8*)&Xq[base] = out;
}

// ---------------- GEMM: C[M][N] = A[M][K] * B[N][K]^T + bias ----------------
// KEY (r6 bug fix): LDAF/LDBF read BOTH half-slots of an operand (wr / wc>>1
// select the half per wave), so a tile-operand's FIRST read requires BOTH of
// its stages landed.
// Pipelined ledger (tiles a=2i[db0], b=2i+1[db1], aN=a+2, bN=b+2):
// phase: vmcnt? | barrier | reads(next phase) | stage | lgkm(own) | MFMA | post
//   P1:        rd a.B1[4]   st b.A0   lg(4) M(A0,B0)
//   P2:        rd a.A1[8]   st b.A1   lg(8) M(A0,B1)
//   P3:        --           st aN.B0  lg(0) M(A1,B1)
//   P4: vm(2)  rd b.A0/1[8] st aN.A0  lg(8) M(A1,B0)  post-rd b.B0/1[4]
//   P5:        rd b.B1[4]   st aN.A1  lg(4) M(A0,B0)
//   P6:        rd b.A1[8]   st aN.B1  lg(8) M(A0,B1)
//   P7:        --           st bN.B0  lg(0) M(A1,B1)
//   P8: vm(2)  rd aN.A[8]   st bN.B1  lg(8) M(A1,B0)  post-rd aN.B[4]
// VM FIFO (2 loads/stage): P4 pre-wait queue [bB0,bB1,bA0,bA1,aNB0] -> vm(2)
//   drains all 4 b-stages (P4+P5+P6 reads covered). P8 pre-wait queue
//   [aNB0,aNA0,aNA1,aNB1,bNB0] -> vm(2) drains all 4 aN-stages (P8+next
//   P1+P2 reads covered). P1/P6 need no wait.
// WAR: every slot's old-data readers drain via an LGKM >=1 barrier before the
//   overwriting stage issues. Last iter re-stages identical bytes (benign).
__global__ __launch_bounds__(512, 2) void gemm_kernel(
    const _Float16* __restrict__ A, const _Float16* __restrict__ B,
    const float* __restrict__ bias, float* __restrict__ C) {
    constexpr int N = 8192, K = 2048;
    constexpr int KT = K / 64;          // 32 K-tiles, 16 iterations
    constexpr int NBN = N / 256;        // 32

    __shared__ char smem[131072];       // A: 0..64K, B: 64K..128K

    // XCD-aware swizzle (nwg = 1024, %8 == 0 -> bijective)
    const int bid = blockIdx.x;
    const int cpx = gridDim.x >> 3;
    const int swzb = (bid & 7) * cpx + (bid >> 3);
    const int bm = swzb / NBN;
    const int bn = swzb % NBN;

    const int t = threadIdx.x;
    const int lane = t & 63;
    const int wid = t >> 6;
    const int wr = wid >> 2;            // 0..1 (M half)
    const int wc = wid & 3;             // 0..3 (N quarter)
    const int l15 = lane & 15;
    const int lq = lane >> 4;

    // staging: half-tile [128 rows][64 k] f16 = 16384 B, linear LDS dest,
    // pre-swizzled global source. T2: byte ^= (row&7)<<4.
    const int d0 = t * 16, d1 = d0 + 8192;
    const int r0 = d0 >> 7, c0 = (((d0 & 127) ^ (((d0 >> 7) & 7) << 4)) >> 1);
    const int r1 = d1 >> 7, c1 = (((d1 & 127) ^ (((d1 >> 7) & 7) << 4)) >> 1);
    const _Float16* Agb = A + (size_t)bm * 256 * K;
    const _Float16* Bgb = B + (size_t)bn * 256 * K;

    // read-side swizzled k-col byte offsets (frag row&7 == l15&7)
    const int cp0 = (lq * 16) ^ ((l15 & 7) << 4);
    const int cp1 = cp0 ^ 64;           // second K-half (bit6 XOR)

    f32x4 acc[8][4] = {};
    f16x8 fA0[4][2], fA1[4][2], fB0[2][2], fB1[2][2];

#define STAGE(GB, RO, DBS, H, KS) do {                                         \
        const _Float16* _g = (GB) + (size_t)((H) * 128) * K + (size_t)(KS) * 64;\
        char* _l = smem + (RO) + ((DBS) * 2 + (H)) * 16384;                    \
        gload_lds16(_g + (size_t)r0 * K + c0, _l + d0);                        \
        gload_lds16(_g + (size_t)r1 * K + c1, _l + d1);                        \
    } while (0)

#define LDAF(dst, DBv, MLO) do {                                               \
        const char* _s = smem + ((DBv) * 2 + wr) * 16384 + l15 * 128;          \
        _Pragma("unroll")                                                      \
        for (int _m = 0; _m < 4; ++_m) {                                       \
            dst[_m][0] = *(const f16x8*)(_s + ((MLO) + _m) * 2048 + cp0);      \
            dst[_m][1] = *(const f16x8*)(_s + ((MLO) + _m) * 2048 + cp1);      \
        }                                                                      \
    } while (0)

#define LDBF(dst, DBv, NLO) do {                                               \
        const char* _s = smem + 65536 + ((DBv) * 2 + (wc >> 1)) * 16384 +      \
                         (wc & 1) * 8192 + l15 * 128;                          \
        _Pragma("unroll")                                                      \
        for (int _n = 0; _n < 2; ++_n) {                                       \
            dst[_n][0] = *(const f16x8*)(_s + ((NLO) + _n) * 2048 + cp0);      \
            dst[_n][1] = *(const f16x8*)(_s + ((NLO) + _n) * 2048 + cp1);      \
        }                                                                      \
    } while (0)

#define QMFMA(MLO, NLO, AF, BF) do {                                           \
        _Pragma("unroll")                                                      \
        for (int _m = 0; _m < 4; ++_m)                                         \
            _Pragma("unroll")                                                  \
            for (int _n = 0; _n < 2; ++_n) {                                   \
                f32x4 _c = acc[(MLO) + _m][(NLO) + _n];                        \
                _c = __builtin_amdgcn_mfma_f32_16x16x32_f16(                   \
                    AF[_m][0], BF[_n][0], _c, 0, 0, 0);                        \
                _c = __builtin_amdgcn_mfma_f32_16x16x32_f16(                   \
                    AF[_m][1], BF[_n][1], _c, 0, 0, 0);                        \
                acc[(MLO) + _m][(NLO) + _n] = _c;                              \
            }                                                                  \
    } while (0)

#define LGKM(NN) do {                                                          \
        asm volatile("s_waitcnt lgkmcnt(" #NN ")" ::: "memory");               \
        __builtin_amdgcn_sched_barrier(0);                                     \
    } while (0)
#define VMC(NN) asm volatile("s_waitcnt vmcnt(" #NN ")" ::: "memory")
#define BAR()   __builtin_amdgcn_s_barrier()
#define PRIO(P) __builtin_amdgcn_s_setprio(P)

    // ---- prologue: stage t0 all + t1.{B0,B1}; wait; read P1 operands ----
    STAGE(Bgb, 65536, 0, 0, 0);   // t0.B0
    STAGE(Agb, 0,     0, 0, 0);   // t0.A0
    STAGE(Agb, 0,     0, 1, 0);   // t0.A1
    STAGE(Bgb, 65536, 0, 1, 0);   // t0.B1
    STAGE(Bgb, 65536, 1, 0, 1);   // t1.B0
    STAGE(Bgb, 65536, 1, 1, 1);   // t1.B1
    VMC(4);                       // all t0.* landed; t1.B0/B1 in flight
    BAR();
    LDAF(fA0, 0, 0);              // t0.A rows 0-63
    LDBF(fB0, 0, 0);              // t0.B rows 0-31

    for (int it = 0; it < KT / 2; ++it) {
        const int b  = 2 * it + 1;
        const int aN = (2 * it + 2 < KT) ? 2 * it + 2 : KT - 2;
        const int bN = (2 * it + 3 < KT) ? 2 * it + 3 : KT - 1;

        // ---- tile a (db0) ----
        // P1
        BAR();
        LDBF(fB1, 0, 2);              // a.B rows 32-63
        STAGE(Agb, 0, 1, 0, b);       // b.A0
        LGKM(4);
        PRIO(1); QMFMA(0, 0, fA0, fB0); PRIO(0);
        // P2
        BAR();
        LDAF(fA1, 0, 4);              // a.A rows 64-127
        STAGE(Agb, 0, 1, 1, b);       // b.A1
        LGKM(8);
        PRIO(1); QMFMA(0, 2, fA0, fB1); PRIO(0);
        // P3
        BAR();
        STAGE(Bgb, 65536, 0, 0, aN);  // aN.B0
        LGKM(0);
        PRIO(1); QMFMA(4, 2, fA1, fB1); PRIO(0);
        // P4 (vm(2): drains b.A0,b.A1,b.B0,b.B1)
        VMC(2);
        BAR();
        LDAF(fA0, 1, 0);              // b.A rows 0-63
        STAGE(Agb, 0, 0, 0, aN);      // aN.A0
        LGKM(8);
        PRIO(1); QMFMA(4, 0, fA1, fB0); PRIO(0);
        LDBF(fB0, 1, 0);              // b.B rows 0-31 (post-read)

        // ---- tile b (db1) ----
        // P5
        BAR();
        LDBF(fB1, 1, 2);              // b.B rows 32-63
        STAGE(Agb, 0, 0, 1, aN);      // aN.A1
        LGKM(4);
        PRIO(1); QMFMA(0, 0, fA0, fB0); PRIO(0);
        // P6
        BAR();
        LDAF(fA1, 1, 4);              // b.A rows 64-127
        STAGE(Bgb, 65536, 0, 1, aN);  // aN.B1
        LGKM(8);
        PRIO(1); QMFMA(0, 2, fA0, fB1); PRIO(0);
        // P7
        BAR();
        STAGE(Bgb, 65536, 1, 0, bN);  // bN.B0
        LGKM(0);
        PRIO(1); QMFMA(4, 2, fA1, fB1); PRIO(0);
        // P8 (vm(2): drains aN.B0,aN.A0,aN.A1,aN.B1)
        VMC(2);
        BAR();
        LDAF(fA0, 0, 0);              // aN.A rows 0-63
        STAGE(Bgb, 65536, 1, 1, bN);  // bN.B1
        LGKM(8);
        PRIO(1); QMFMA(4, 0, fA1, fB0); PRIO(0);
        LDBF(fB0, 0, 0);              // aN.B rows 0-31 (post-read)
    }
#undef STAGE
#undef LDAF
#undef LDBF
#undef QMFMA
#undef LGKM
#undef VMC
#undef BAR
#undef PRIO

    // ---- epilogue: C/D mapping col=lane&15, row=(lane>>4)*4+reg ----
#pragma unroll
    for (int m = 0; m < 8; ++m) {
        const int row = bm * 256 + wr * 128 + m * 16 + lq * 4;
#pragma unroll
        for (int n = 0; n < 4; ++n) {
            const int col = bn * 256 + wc * 64 + n * 16 + l15;
            const float bv = bias[col];
#pragma unroll
            for (int r = 0; r < 4; ++r) {
                C[(size_t)(row + r) * N + col] = acc[m][n][r] + bv;
            }
        }
    }
}

extern "C" void kernel_launch(void* const* d_in, const int* in_sizes, int n_in,
                              void* d_out, int out_size, void* d_ws, size_t ws_size,
                              hipStream_t stream) {
    const float* x    = (const float*)d_in[0];   // [4,2048,2048]
    const float* w    = (const float*)d_in[1];   // [8192,2048]
    const float* bias = (const float*)d_in[2];   // [8192]
    const float* las  = (const float*)d_in[3];   // log_act_s [1]
    const float* laq  = (const float*)d_in[4];   // log_act_q [1]
    const float* ab   = (const float*)d_in[5];   // act_b [1]
    const float* lws  = (const float*)d_in[6];   // log_wght_s [8192]
    float* out = (float*)d_out;

    constexpr size_t MK = (size_t)8192 * 2048;
    _Float16* xq = (_Float16*)d_ws;
    _Float16* wq = (_Float16*)((char*)d_ws + MK * sizeof(_Float16));

    xquant_kernel<<<8192, 256, 0, stream>>>(x, las, laq, ab, xq);
    wquant_kernel<<<8192, 256, 0, stream>>>(w, lws, wq);
    gemm_kernel<<<1024, 512, 0, stream>>>(xq, wq, bias, out);
}